// Round 2
// baseline (432.665 us; speedup 1.0000x reference)
//
#include <hip/hip_runtime.h>
#include <math.h>

#define IN_F 2048
#define OUT_F 2048
#define BATCH 2048

typedef float4 f4;

// ------------------------------------------------------------------
// ws layout (floats):
//   [0,      2048)  invnorm[i]  = 1/||w_row_i||
//   [2048,  18432)  ldb[256][8][8]
//   [18432, 20480)  expld[j]    = exp(log_diag[j])
//   [20480, 22528)  my[256][8]  = colmax_k ldb[d][k][j]
//   [22528, 38912)  eY[256][64] = exp(ldb - my)
// ------------------------------------------------------------------

// One block per weight row: masked sum-of-squares -> invnorm, ldb entries.
__global__ __launch_bounds__(256) void prep_rows_k(const float* __restrict__ weight,
                                                   const float* __restrict__ log_diag,
                                                   float* __restrict__ invnorm,
                                                   float* __restrict__ ldb) {
    const int i  = blockIdx.x;      // row 0..2047
    const int ri = i >> 3;          // row block index
    const int t  = threadIdx.x;     // == column block index cj (8 cols per thread)
    const f4* wrow = reinterpret_cast<const f4*>(weight + (size_t)i * OUT_F);
    f4 v0 = wrow[t * 2];
    f4 v1 = wrow[t * 2 + 1];
    float raw[8] = {v0.x, v0.y, v0.z, v0.w, v1.x, v1.y, v1.z, v1.w};

    float ss = 0.0f;
    if (t == ri) {
        #pragma unroll
        for (int e = 0; e < 8; ++e) { float m = expf(raw[e]); ss += m * m; }
    } else if (t > ri) {
        #pragma unroll
        for (int e = 0; e < 8; ++e) ss += raw[e] * raw[e];
    }
    // wave64 reduce + cross-wave via LDS
    #pragma unroll
    for (int o = 32; o > 0; o >>= 1) ss += __shfl_xor(ss, o, 64);
    __shared__ float part[4];
    if ((t & 63) == 0) part[t >> 6] = ss;
    __syncthreads();
    float total = part[0] + part[1] + part[2] + part[3];
    float norm  = sqrtf(total);

    if (t == 0) invnorm[i] = 1.0f / norm;
    if (t == ri) {  // this thread holds the diagonal block entries of this row
        float logn = logf(norm);
        int a = i & 7;
        #pragma unroll
        for (int b = 0; b < 8; ++b)
            ldb[ri * 64 + a * 8 + b] = log_diag[ri * 8 + b] + raw[b] - logn;
    }
}

// 2048 threads: one (d,j) pair each -> my, eY; plus expld.
__global__ __launch_bounds__(256) void prep_ldb_k(const float* __restrict__ ldb,
                                                  const float* __restrict__ log_diag,
                                                  float* __restrict__ myv,
                                                  float* __restrict__ eY,
                                                  float* __restrict__ expld) {
    int t = blockIdx.x * 256 + threadIdx.x;   // 0..2047
    expld[t] = expf(log_diag[t]);
    int d = t >> 3, j = t & 7;
    float m = -INFINITY;
    #pragma unroll
    for (int k = 0; k < 8; ++k) m = fmaxf(m, ldb[d * 64 + k * 8 + j]);
    myv[t] = m;
    #pragma unroll
    for (int k = 0; k < 8; ++k) eY[d * 64 + k * 8 + j] = expf(ldb[d * 64 + k * 8 + j] - m);
}

// ------------------------------------------------------------------
// Triangular fp32 GEMM, paired-strip version.
// 256 blocks = 16 M-tiles (128 rows) x 16 column pairs.
// Each block owns strips jL = q*64 and jR = (31-q)*64: per-block FMA work
// is proportional to KL+KR = 2112 -> uniform across all blocks.
// 256 threads, 8x8 micro-tile (8 rows x (4 cols L + 4 cols R)).
// BK=16, double-buffered LDS, one barrier per K-step, ordered so the
// barrier's vmcnt drain never waits on the prefetch loads.
// ------------------------------------------------------------------
__global__ __launch_bounds__(256, 1) void gemm_tri2_k(const float* __restrict__ x,
                                                      const float* __restrict__ weight,
                                                      const float* __restrict__ invnorm,
                                                      const float* __restrict__ expld,
                                                      const float* __restrict__ bias,
                                                      float* __restrict__ y) {
    __shared__ float lsA[2][16 * 136];   // [k][m] transposed, pad 136
    __shared__ float lsB[2][16 * 128];   // [k][ 0..63 = strip L | 64..127 = strip R ]

    const int b  = blockIdx.x;
    const int it = b & 15;
    const int q  = b >> 4;               // 0..15
    const int m0 = it * 128;
    const int jL = q * 64;
    const int jR = (31 - q) * 64;
    const int KL = jL + 64;
    const int KR = jR + 64;

    const int t  = threadIdx.x;
    const int tx = t & 15;               // column quad within strip
    const int ty = t >> 4;               // row group (8 rows)
    const int cA = t & 3,  mA = t >> 2;  // A staging: k-quad, row
    const int kB = t >> 4, j4 = t & 15;  // B staging: k row, col quad

    const f4 elL = *reinterpret_cast<const f4*>(expld + jL + j4 * 4);
    const f4 elR = *reinterpret_cast<const f4*>(expld + jR + j4 * 4);
    const int cjL = (jL + j4 * 4) >> 3;
    const int cjR = (jR + j4 * 4) >> 3;

    float accL[8][4], accR[8][4];
    #pragma unroll
    for (int r = 0; r < 8; ++r)
        #pragma unroll
        for (int c = 0; c < 4; ++c) { accL[r][c] = 0.0f; accR[r][c] = 0.0f; }

    // prefetch registers
    f4 rA0, rA1, rBL, rBR;
    float rInv;

    // ---- issue tile k0 ----
    #define ISSUE(k0, fullf)                                                          \
        do {                                                                          \
            rA0 = *reinterpret_cast<const f4*>(x + (size_t)(m0 + mA) * IN_F + (k0) + cA * 4);        \
            rA1 = *reinterpret_cast<const f4*>(x + (size_t)(m0 + mA + 64) * IN_F + (k0) + cA * 4);   \
            int k_ = (k0) + kB;                                                       \
            rInv = invnorm[k_];                                                       \
            rBR = *reinterpret_cast<const f4*>(weight + (size_t)k_ * OUT_F + jR + j4 * 4);           \
            if (fullf)                                                                \
                rBL = *reinterpret_cast<const f4*>(weight + (size_t)k_ * OUT_F + jL + j4 * 4);       \
        } while (0)

    ISSUE(0, true);
    const int nt = KR >> 4;
    int buf = 0;
    for (int i = 0; i < nt; ++i) {
        const int k0  = i << 4;
        const bool full = (k0 < KL);
        // ---- commit prefetched tile to LDS (implicit vmcnt wait on reg use) ----
        {
            float* A = lsA[buf];
            float* B = lsB[buf];
            A[(cA * 4 + 0) * 136 + mA]      = rA0.x;
            A[(cA * 4 + 1) * 136 + mA]      = rA0.y;
            A[(cA * 4 + 2) * 136 + mA]      = rA0.z;
            A[(cA * 4 + 3) * 136 + mA]      = rA0.w;
            A[(cA * 4 + 0) * 136 + mA + 64] = rA1.x;
            A[(cA * 4 + 1) * 136 + mA + 64] = rA1.y;
            A[(cA * 4 + 2) * 136 + mA + 64] = rA1.z;
            A[(cA * 4 + 3) * 136 + mA + 64] = rA1.w;
            const int rk = (k0 + kB) >> 3;
            f4 o;
            if (cjR < rk) { o.x = o.y = o.z = o.w = 0.0f; }
            else if (cjR == rk) {
                o.x = expf(rBR.x) * rInv * elR.x; o.y = expf(rBR.y) * rInv * elR.y;
                o.z = expf(rBR.z) * rInv * elR.z; o.w = expf(rBR.w) * rInv * elR.w;
            } else {
                o.x = rBR.x * rInv * elR.x; o.y = rBR.y * rInv * elR.y;
                o.z = rBR.z * rInv * elR.z; o.w = rBR.w * rInv * elR.w;
            }
            *reinterpret_cast<f4*>(&B[kB * 128 + 64 + j4 * 4]) = o;
            if (full) {
                f4 p;
                if (cjL < rk) { p.x = p.y = p.z = p.w = 0.0f; }
                else if (cjL == rk) {
                    p.x = expf(rBL.x) * rInv * elL.x; p.y = expf(rBL.y) * rInv * elL.y;
                    p.z = expf(rBL.z) * rInv * elL.z; p.w = expf(rBL.w) * rInv * elL.w;
                } else {
                    p.x = rBL.x * rInv * elL.x; p.y = rBL.y * rInv * elL.y;
                    p.z = rBL.z * rInv * elL.z; p.w = rBL.w * rInv * elL.w;
                }
                *reinterpret_cast<f4*>(&B[kB * 128 + j4 * 4]) = p;
            }
        }
        __syncthreads();   // vmem queue is empty here: no drain stall
        // ---- issue next tile; loads fly under the compute below ----
        const int k0n = k0 + 16;
        if (i + 1 < nt) { bool fn = (k0n < KL); ISSUE(k0n, fn); }
        // ---- compute from LDS[buf] ----
        {
            const float* A = lsA[buf];
            const float* B = lsB[buf];
            if (full) {
                #pragma unroll
                for (int kk = 0; kk < 16; ++kk) {
                    f4 a0 = *reinterpret_cast<const f4*>(A + kk * 136 + ty * 8);
                    f4 a1 = *reinterpret_cast<const f4*>(A + kk * 136 + ty * 8 + 4);
                    f4 bL = *reinterpret_cast<const f4*>(B + kk * 128 + tx * 4);
                    f4 bR = *reinterpret_cast<const f4*>(B + kk * 128 + 64 + tx * 4);
                    float am[8] = {a0.x, a0.y, a0.z, a0.w, a1.x, a1.y, a1.z, a1.w};
                    float bl[4] = {bL.x, bL.y, bL.z, bL.w};
                    float br[4] = {bR.x, bR.y, bR.z, bR.w};
                    #pragma unroll
                    for (int r = 0; r < 8; ++r) {
                        #pragma unroll
                        for (int c = 0; c < 4; ++c) {
                            accL[r][c] = fmaf(am[r], bl[c], accL[r][c]);
                            accR[r][c] = fmaf(am[r], br[c], accR[r][c]);
                        }
                    }
                }
            } else {
                #pragma unroll
                for (int kk = 0; kk < 16; ++kk) {
                    f4 a0 = *reinterpret_cast<const f4*>(A + kk * 136 + ty * 8);
                    f4 a1 = *reinterpret_cast<const f4*>(A + kk * 136 + ty * 8 + 4);
                    f4 bR = *reinterpret_cast<const f4*>(B + kk * 128 + 64 + tx * 4);
                    float am[8] = {a0.x, a0.y, a0.z, a0.w, a1.x, a1.y, a1.z, a1.w};
                    float br[4] = {bR.x, bR.y, bR.z, bR.w};
                    #pragma unroll
                    for (int r = 0; r < 8; ++r)
                        #pragma unroll
                        for (int c = 0; c < 4; ++c)
                            accR[r][c] = fmaf(am[r], br[c], accR[r][c]);
                }
            }
        }
        buf ^= 1;
    }
    #undef ISSUE

    // ---- epilogue ----
    f4 bbL = *reinterpret_cast<const f4*>(bias + jL + tx * 4);
    f4 bbR = *reinterpret_cast<const f4*>(bias + jR + tx * 4);
    #pragma unroll
    for (int r = 0; r < 8; ++r) {
        const size_t row = m0 + ty * 8 + r;
        f4 oL, oR;
        oL.x = accL[r][0] + bbL.x; oL.y = accL[r][1] + bbL.y;
        oL.z = accL[r][2] + bbL.z; oL.w = accL[r][3] + bbL.w;
        oR.x = accR[r][0] + bbR.x; oR.y = accR[r][1] + bbR.y;
        oR.z = accR[r][2] + bbR.z; oR.w = accR[r][3] + bbR.w;
        *reinterpret_cast<f4*>(y + row * OUT_F + jL + tx * 4) = oL;
        *reinterpret_cast<f4*>(y + row * OUT_F + jR + tx * 4) = oR;
    }
}

// Streaming 8x8 log-matmul: one thread per 8-element row of a tile.
__global__ __launch_bounds__(256) void accum_k(const float* __restrict__ ab,
                                               const float* __restrict__ eY,
                                               const float* __restrict__ myv,
                                               float* __restrict__ out) {
    __shared__ float lsE[32 * 68];   // pad 68 -> conflict-free broadcast reads
    __shared__ float lsM[256];

    const int blk = blockIdx.x;
    const int t   = threadIdx.x;
    const int tile0 = blk * 32;
    const int d0    = tile0 & 255;   // 32 | 256: a block never straddles a batch

    #pragma unroll
    for (int h = 0; h < 2; ++h) {
        int idx4 = t + h * 256;
        int lin  = idx4 * 4;
        int dd = lin >> 6, c = lin & 63;
        f4 v = *reinterpret_cast<const f4*>(eY + d0 * 64 + lin);
        *reinterpret_cast<f4*>(&lsE[dd * 68 + c]) = v;
    }
    lsM[t] = myv[d0 * 8 + t];
    __syncthreads();

    const size_t r = (size_t)blk * 256 + t;
    const f4* lxp = reinterpret_cast<const f4*>(ab + r * 8);
    f4 l0 = lxp[0], l1 = lxp[1];
    float lx[8] = {l0.x, l0.y, l0.z, l0.w, l1.x, l1.y, l1.z, l1.w};

    float mx = lx[0];
    #pragma unroll
    for (int k = 1; k < 8; ++k) mx = fmaxf(mx, lx[k]);
    float el[8];
    #pragma unroll
    for (int k = 0; k < 8; ++k) el[k] = expf(lx[k] - mx);

    const int dd = t >> 3;
    float o[8];
    #pragma unroll
    for (int j = 0; j < 8; ++j) {
        float s = 0.0f;
        #pragma unroll
        for (int k = 0; k < 8; ++k)
            s = fmaf(el[k], lsE[dd * 68 + k * 8 + j], s);
        o[j] = logf(s) + mx + lsM[dd * 8 + j];
    }
    f4 o0 = {o[0], o[1], o[2], o[3]};
    f4 o1 = {o[4], o[5], o[6], o[7]};
    f4* op = reinterpret_cast<f4*>(out + r * 8);
    op[0] = o0; op[1] = o1;
}

extern "C" void kernel_launch(void* const* d_in, const int* in_sizes, int n_in,
                              void* d_out, int out_size, void* d_ws, size_t ws_size,
                              hipStream_t stream) {
    const float* x        = (const float*)d_in[0];
    const float* ab       = (const float*)d_in[1];
    const float* weight   = (const float*)d_in[2];
    const float* log_diag = (const float*)d_in[3];
    const float* bias     = (const float*)d_in[4];

    float* y     = (float*)d_out;
    float* accum = (float*)d_out + (size_t)BATCH * OUT_F;

    float* ws      = (float*)d_ws;
    float* invnorm = ws;
    float* ldb     = ws + 2048;
    float* expld   = ws + 18432;
    float* myv     = ws + 20480;
    float* eY      = ws + 22528;

    hipLaunchKernelGGL(prep_rows_k, dim3(2048), dim3(256), 0, stream,
                       weight, log_diag, invnorm, ldb);
    hipLaunchKernelGGL(prep_ldb_k, dim3(8), dim3(256), 0, stream,
                       ldb, log_diag, myv, eY, expld);
    hipLaunchKernelGGL(gemm_tri2_k, dim3(256), dim3(256), 0, stream,
                       x, weight, invnorm, expld, bias, y);
    hipLaunchKernelGGL(accum_k, dim3(16384), dim3(256), 0, stream,
                       ab, eY, myv, accum);
}

// Round 3
// 352.947 us; speedup vs baseline: 1.2259x; 1.2259x over previous
//
#include <hip/hip_runtime.h>
#include <math.h>

#define IN_F 2048
#define OUT_F 2048
#define BATCH 2048

typedef float4 f4;
typedef __attribute__((ext_vector_type(4))) float f32x4;
typedef __attribute__((ext_vector_type(8))) short bf16x8;
typedef __attribute__((ext_vector_type(4))) short bf16x4;

__device__ inline unsigned short f2bh(float f) {   // f32 -> bf16 bits, RNE
    unsigned u = __float_as_uint(f);
    u += 0x7FFF + ((u >> 16) & 1);
    return (unsigned short)(u >> 16);
}
__device__ inline float bh2f(unsigned short h) {
    return __uint_as_float(((unsigned)h) << 16);
}

// ------------------------------------------------------------------
// ws layout (floats):
//   [0,      2048)  invnorm[i]  = 1/||w_row_i||
//   [2048,  18432)  ldb[256][8][8]
//   [18432, 20480)  expld[j]    = exp(log_diag[j])
//   [20480, 22528)  my[256][8]
//   [22528, 38912)  eY[256][64]
// ------------------------------------------------------------------

__global__ __launch_bounds__(256) void prep_rows_k(const float* __restrict__ weight,
                                                   const float* __restrict__ log_diag,
                                                   float* __restrict__ invnorm,
                                                   float* __restrict__ ldb) {
    const int i  = blockIdx.x;
    const int ri = i >> 3;
    const int t  = threadIdx.x;
    const f4* wrow = reinterpret_cast<const f4*>(weight + (size_t)i * OUT_F);
    f4 v0 = wrow[t * 2];
    f4 v1 = wrow[t * 2 + 1];
    float raw[8] = {v0.x, v0.y, v0.z, v0.w, v1.x, v1.y, v1.z, v1.w};

    float ss = 0.0f;
    if (t == ri) {
        #pragma unroll
        for (int e = 0; e < 8; ++e) { float m = expf(raw[e]); ss += m * m; }
    } else if (t > ri) {
        #pragma unroll
        for (int e = 0; e < 8; ++e) ss += raw[e] * raw[e];
    }
    #pragma unroll
    for (int o = 32; o > 0; o >>= 1) ss += __shfl_xor(ss, o, 64);
    __shared__ float part[4];
    if ((t & 63) == 0) part[t >> 6] = ss;
    __syncthreads();
    float total = part[0] + part[1] + part[2] + part[3];
    float norm  = sqrtf(total);

    if (t == 0) invnorm[i] = 1.0f / norm;
    if (t == ri) {
        float logn = logf(norm);
        int a = i & 7;
        #pragma unroll
        for (int b = 0; b < 8; ++b)
            ldb[ri * 64 + a * 8 + b] = log_diag[ri * 8 + b] + raw[b] - logn;
    }
}

__global__ __launch_bounds__(256) void prep_ldb_k(const float* __restrict__ ldb,
                                                  const float* __restrict__ log_diag,
                                                  float* __restrict__ myv,
                                                  float* __restrict__ eY,
                                                  float* __restrict__ expld) {
    int t = blockIdx.x * 256 + threadIdx.x;
    expld[t] = expf(log_diag[t]);
    int d = t >> 3, j = t & 7;
    float m = -INFINITY;
    #pragma unroll
    for (int k = 0; k < 8; ++k) m = fmaxf(m, ldb[d * 64 + k * 8 + j]);
    myv[t] = m;
    #pragma unroll
    for (int k = 0; k < 8; ++k) eY[d * 64 + k * 8 + j] = expf(ldb[d * 64 + k * 8 + j] - m);
}

// ------------------------------------------------------------------
// Split-bf16 MFMA GEMM: y = (x*invnorm_k) @ mask(w) * expld_n + bias.
// 512 blocks = 32 M-tiles (64 rows) x 16 strip-pairs (strips of 64 cols,
// pair (q, 31-q) -> per-block MFMA work exactly constant = 792/wave).
// 256 thr / 4 waves; wave = 32 rows x (32 L-cols + 32 R-cols) = 2x4 tiles
// of 16x16.  BK=32, 3 MFMAs per tile-k (hi*hi + lo*hi + hi*lo).
// LDS: [row][32k] bf16 tiles, XOR-swizzled 16B chunks (4 rows / 256B line)
// -> conflict-free ds_read_b128 fragments.  Double-buffered, 1 barrier/step.
// ------------------------------------------------------------------
#define BK 32
#define TILE_BYTES 24576   // A_hi 4K | A_lo 4K | B_hi 8K | B_lo 8K

__device__ inline int swz(int row, int kc) {   // byte offset of 16B chunk
    int R = row >> 2;
    int c = ((row & 3) << 2) | kc;
    return (R << 8) | (((c ^ (R & 15)) & 15) << 4);
}

__global__ __launch_bounds__(256, 3) void gemm_mfma_k(const float* __restrict__ x,
                                                      const float* __restrict__ weight,
                                                      const float* __restrict__ invnorm,
                                                      const float* __restrict__ expld,
                                                      const float* __restrict__ bias,
                                                      float* __restrict__ y) {
    __shared__ char lds[2 * TILE_BYTES];

    const int b  = blockIdx.x;
    const int q  = (b & 7) | (((b >> 8) & 1) << 3);   // 0..15, same-q -> same XCD
    const int it = (b >> 3) & 31;                     // 0..31
    const int m0 = it * 64;
    const int jL = q * 64;
    const int jR = (31 - q) * 64;
    const int KL = jL + 64;
    const int KR = jR + 64;
    const int nt  = KR >> 5;
    const int ntL = KL >> 5;

    const int tid = threadIdx.x;
    const int l   = tid & 63;
    const int w   = tid >> 6;
    const int wr  = w >> 1, wc = w & 1;
    const int l15 = l & 15, h = (l >> 4) & 3;

    // ---- A staging descriptors: fi = tid + 256*i -> (m = fi>>3, c8 = fi&7) ----
    int mA[2], koA[2], wbA[2];
    #pragma unroll
    for (int i = 0; i < 2; ++i) {
        int fi = tid + (i << 8);
        mA[i] = fi >> 3;
        int c8 = fi & 7;
        koA[i] = c8 << 2;
        wbA[i] = swz(mA[i], c8 >> 1) + ((c8 & 1) << 3);
    }
    // ---- B staging: strip sB, column n, k-half ----
    const int sB  = tid >> 7;          // 0 = L strip, 1 = R strip
    const int tt  = tid & 127;
    const int nB  = tt & 63;
    const int kh  = tt >> 6;           // k offset 16*kh
    const int ngB = (sB ? jR : jL) + nB;
    const int cjB = ngB >> 3;
    const int rB  = (sB << 6) + nB;
    const int wbB0 = swz(rB, kh << 1);
    const int wbB1 = swz(rB, (kh << 1) | 1);

    // ---- fragment read offsets (constant per thread) ----
    int raA[2], raB[4];
    #pragma unroll
    for (int mi = 0; mi < 2; ++mi) raA[mi] = swz(32 * wr + 16 * mi + l15, h);
    #pragma unroll
    for (int nj = 0; nj < 4; ++nj) {
        int rb = ((nj >> 1) << 6) + 32 * wc + ((nj & 1) << 4);
        raB[nj] = swz(rb + l15, h);
    }

    f32x4 acc[2][4];
    #pragma unroll
    for (int mi = 0; mi < 2; ++mi)
        #pragma unroll
        for (int nj = 0; nj < 4; ++nj) acc[mi][nj] = (f32x4)0.0f;

    f4 rxa[2], riva[2];
    float rw[16];

    auto LOAD = [&](int k0) {
        #pragma unroll
        for (int i = 0; i < 2; ++i) {
            rxa[i]  = *reinterpret_cast<const f4*>(x + (size_t)(m0 + mA[i]) * IN_F + k0 + koA[i]);
            riva[i] = *reinterpret_cast<const f4*>(invnorm + k0 + koA[i]);
        }
        if (sB || (k0 < KL)) {
            #pragma unroll
            for (int i = 0; i < 16; ++i)
                rw[i] = weight[(size_t)(k0 + (kh << 4) + i) * OUT_F + ngB];
        }
    };

    auto COMMIT = [&](int k0, int buf) {
        char* base = lds + buf * TILE_BYTES;
        #pragma unroll
        for (int i = 0; i < 2; ++i) {
            bf16x4 h4, l4;
            const float* xp = reinterpret_cast<const float*>(&rxa[i]);
            const float* ip = reinterpret_cast<const float*>(&riva[i]);
            #pragma unroll
            for (int c = 0; c < 4; ++c) {
                float xs = xp[c] * ip[c];
                unsigned short hb = f2bh(xs);
                h4[c] = (short)hb;
                l4[c] = (short)f2bh(xs - bh2f(hb));
            }
            *reinterpret_cast<bf16x4*>(base + wbA[i]) = h4;
            *reinterpret_cast<bf16x4*>(base + 4096 + wbA[i]) = l4;
        }
        if (sB || (k0 < KL)) {
            bf16x8 h8a, l8a, h8b, l8b;
            #pragma unroll
            for (int i = 0; i < 16; ++i) {
                int k  = k0 + (kh << 4) + i;
                int rk = k >> 3;
                float v = (cjB < rk) ? 0.0f : ((cjB == rk) ? __expf(rw[i]) : rw[i]);
                unsigned short hb = f2bh(v);
                unsigned short lb = f2bh(v - bh2f(hb));
                if (i < 8) { h8a[i] = (short)hb; l8a[i] = (short)lb; }
                else       { h8b[i - 8] = (short)hb; l8b[i - 8] = (short)lb; }
            }
            *reinterpret_cast<bf16x8*>(base + 8192  + wbB0) = h8a;
            *reinterpret_cast<bf16x8*>(base + 8192  + wbB1) = h8b;
            *reinterpret_cast<bf16x8*>(base + 16384 + wbB0) = l8a;
            *reinterpret_cast<bf16x8*>(base + 16384 + wbB1) = l8b;
        }
    };

    LOAD(0);
    COMMIT(0, 0);
    if (nt > 1) LOAD(BK);
    __syncthreads();

    for (int t = 0; t < nt; ++t) {
        const int cur = t & 1;
        if (t + 1 < nt) COMMIT((t + 1) << 5, cur ^ 1);
        if (t + 2 < nt) LOAD((t + 2) << 5);
        {
            const char* base = lds + cur * TILE_BYTES;
            const bool full = (t < ntL);
            bf16x8 ah[2], al[2], bh[4], bl[4];
            #pragma unroll
            for (int mi = 0; mi < 2; ++mi) {
                ah[mi] = *reinterpret_cast<const bf16x8*>(base + raA[mi]);
                al[mi] = *reinterpret_cast<const bf16x8*>(base + 4096 + raA[mi]);
            }
            #pragma unroll
            for (int nj = 0; nj < 4; ++nj) {
                if (nj >= 2 || full) {
                    bh[nj] = *reinterpret_cast<const bf16x8*>(base + 8192  + raB[nj]);
                    bl[nj] = *reinterpret_cast<const bf16x8*>(base + 16384 + raB[nj]);
                }
            }
            #pragma unroll
            for (int mi = 0; mi < 2; ++mi)
                #pragma unroll
                for (int nj = 0; nj < 4; ++nj) {
                    if (nj >= 2 || full) {
                        acc[mi][nj] = __builtin_amdgcn_mfma_f32_16x16x32_bf16(ah[mi], bh[nj], acc[mi][nj], 0, 0, 0);
                        acc[mi][nj] = __builtin_amdgcn_mfma_f32_16x16x32_bf16(al[mi], bh[nj], acc[mi][nj], 0, 0, 0);
                        acc[mi][nj] = __builtin_amdgcn_mfma_f32_16x16x32_bf16(ah[mi], bl[nj], acc[mi][nj], 0, 0, 0);
                    }
                }
        }
        __syncthreads();
    }

    // ---- epilogue: y = acc * expld[col] + bias[col] ----
    #pragma unroll
    for (int mi = 0; mi < 2; ++mi)
        #pragma unroll
        for (int nj = 0; nj < 4; ++nj) {
            int nb  = ((nj >> 1) ? jR : jL) + 32 * wc + ((nj & 1) << 4);
            int col = nb + l15;
            float el = expld[col];
            float bs = bias[col];
            #pragma unroll
            for (int j = 0; j < 4; ++j) {
                int row = m0 + 32 * wr + 16 * mi + ((l >> 4) << 2) + j;
                y[(size_t)row * OUT_F + col] = ((const float*)&acc[mi][nj])[j] * el + bs;
            }
        }
}

// Streaming 8x8 log-matmul (HW transcendentals).
__global__ __launch_bounds__(256) void accum_k(const float* __restrict__ ab,
                                               const float* __restrict__ eY,
                                               const float* __restrict__ myv,
                                               float* __restrict__ out) {
    __shared__ float lsE[32 * 68];
    __shared__ float lsM[256];

    const int blk = blockIdx.x;
    const int t   = threadIdx.x;
    const int d0  = (blk * 32) & 255;

    #pragma unroll
    for (int hh = 0; hh < 2; ++hh) {
        int idx4 = t + hh * 256;
        int lin  = idx4 * 4;
        int dd = lin >> 6, c = lin & 63;
        f4 v = *reinterpret_cast<const f4*>(eY + d0 * 64 + lin);
        *reinterpret_cast<f4*>(&lsE[dd * 68 + c]) = v;
    }
    lsM[t] = myv[d0 * 8 + t];
    __syncthreads();

    const size_t r = (size_t)blk * 256 + t;
    const f4* lxp = reinterpret_cast<const f4*>(ab + r * 8);
    f4 l0 = lxp[0], l1 = lxp[1];
    float lx[8] = {l0.x, l0.y, l0.z, l0.w, l1.x, l1.y, l1.z, l1.w};

    float mx = lx[0];
    #pragma unroll
    for (int k = 1; k < 8; ++k) mx = fmaxf(mx, lx[k]);
    float el[8];
    #pragma unroll
    for (int k = 0; k < 8; ++k) el[k] = __expf(lx[k] - mx);

    const int dd = t >> 3;
    float o[8];
    #pragma unroll
    for (int j = 0; j < 8; ++j) {
        float s = 0.0f;
        #pragma unroll
        for (int k = 0; k < 8; ++k)
            s = fmaf(el[k], lsE[dd * 68 + k * 8 + j], s);
        o[j] = __logf(s) + mx + lsM[dd * 8 + j];
    }
    f4 o0 = {o[0], o[1], o[2], o[3]};
    f4 o1 = {o[4], o[5], o[6], o[7]};
    f4* op = reinterpret_cast<f4*>(out + r * 8);
    op[0] = o0; op[1] = o1;
}

extern "C" void kernel_launch(void* const* d_in, const int* in_sizes, int n_in,
                              void* d_out, int out_size, void* d_ws, size_t ws_size,
                              hipStream_t stream) {
    const float* x        = (const float*)d_in[0];
    const float* ab       = (const float*)d_in[1];
    const float* weight   = (const float*)d_in[2];
    const float* log_diag = (const float*)d_in[3];
    const float* bias     = (const float*)d_in[4];

    float* y     = (float*)d_out;
    float* accum = (float*)d_out + (size_t)BATCH * OUT_F;

    float* ws      = (float*)d_ws;
    float* invnorm = ws;
    float* ldb     = ws + 2048;
    float* expld   = ws + 18432;
    float* myv     = ws + 20480;
    float* eY      = ws + 22528;

    hipLaunchKernelGGL(prep_rows_k, dim3(2048), dim3(256), 0, stream,
                       weight, log_diag, invnorm, ldb);
    hipLaunchKernelGGL(prep_ldb_k, dim3(8), dim3(256), 0, stream,
                       ldb, log_diag, myv, eY, expld);
    hipLaunchKernelGGL(gemm_mfma_k, dim3(512), dim3(256), 0, stream,
                       x, weight, invnorm, expld, bias, y);
    hipLaunchKernelGGL(accum_k, dim3(16384), dim3(256), 0, stream,
                       ab, eY, myv, accum);
}

// Round 5
// 316.483 us; speedup vs baseline: 1.3671x; 1.1152x over previous
//
#include <hip/hip_runtime.h>
#include <math.h>

#define IN_F 2048
#define OUT_F 2048
#define BATCH 2048

typedef float4 f4;
typedef __attribute__((ext_vector_type(4))) float f32x4;
typedef __attribute__((ext_vector_type(8))) short bf16x8;

__device__ __forceinline__ unsigned short f2bh(float f) {   // f32 -> bf16, RNE
    unsigned u = __float_as_uint(f);
    u += 0x7FFF + ((u >> 16) & 1);
    return (unsigned short)(u >> 16);
}
__device__ __forceinline__ float bh2f(unsigned short h) {
    return __uint_as_float(((unsigned)h) << 16);
}

__device__ __forceinline__ void gload16(const char* g, char* l) {
    __builtin_amdgcn_global_load_lds(
        (const __attribute__((address_space(1))) unsigned int*)g,
        (__attribute__((address_space(3))) unsigned int*)l, 16, 0, 0);
}

// ------------------------------------------------------------------
// ws (floats): invnorm@0[2048] | ldb@2048[16384] | expld@18432[2048]
//              | myv@20480[2048] | eY@22528[16384]
// scratch (= d_out accum region, byte offsets):
//   A_HI@0  A_LO@8M  B_HI@16M  B_LO@24M   (tiled bf16 images)
// Tile = 64 rows x 32 k bf16 = 4096 B, addressed (rt*64 + kt)*4096.
// Within tile: byte = row*64 + chunk*16; chunk c holds k-chunk
// h = (c ^ (row>>1)) & 3 (8 bf16). This is EXACTLY the LDS image, so
// global_load_lds is a linear byte copy, and swizzled ds_read_b128
// fragment reads are 2-way-conflict (free per m136).
// ------------------------------------------------------------------

__global__ __launch_bounds__(256) void prep_rows_k(const float* __restrict__ weight,
                                                   const float* __restrict__ log_diag,
                                                   float* __restrict__ invnorm,
                                                   float* __restrict__ ldb) {
    const int i  = blockIdx.x;
    const int ri = i >> 3;
    const int t  = threadIdx.x;
    const f4* wrow = reinterpret_cast<const f4*>(weight + (size_t)i * OUT_F);
    f4 v0 = wrow[t * 2];
    f4 v1 = wrow[t * 2 + 1];
    float raw[8] = {v0.x, v0.y, v0.z, v0.w, v1.x, v1.y, v1.z, v1.w};

    float ss = 0.0f;
    if (t == ri) {
        #pragma unroll
        for (int e = 0; e < 8; ++e) { float m = expf(raw[e]); ss += m * m; }
    } else if (t > ri) {
        #pragma unroll
        for (int e = 0; e < 8; ++e) ss += raw[e] * raw[e];
    }
    #pragma unroll
    for (int o = 32; o > 0; o >>= 1) ss += __shfl_xor(ss, o, 64);
    __shared__ float part[4];
    if ((t & 63) == 0) part[t >> 6] = ss;
    __syncthreads();
    float total = part[0] + part[1] + part[2] + part[3];
    float norm  = sqrtf(total);

    if (t == 0) invnorm[i] = 1.0f / norm;
    if (t == ri) {
        float logn = logf(norm);
        int a = i & 7;
        #pragma unroll
        for (int b = 0; b < 8; ++b)
            ldb[ri * 64 + a * 8 + b] = log_diag[ri * 8 + b] + raw[b] - logn;
    }
}

__global__ __launch_bounds__(256) void prep_ldb_k(const float* __restrict__ ldb,
                                                  const float* __restrict__ log_diag,
                                                  float* __restrict__ myv,
                                                  float* __restrict__ eY,
                                                  float* __restrict__ expld) {
    int t = blockIdx.x * 256 + threadIdx.x;
    expld[t] = expf(log_diag[t]);
    int d = t >> 3, j = t & 7;
    float m = -INFINITY;
    #pragma unroll
    for (int k = 0; k < 8; ++k) m = fmaxf(m, ldb[d * 64 + k * 8 + j]);
    myv[t] = m;
    #pragma unroll
    for (int k = 0; k < 8; ++k) eY[d * 64 + k * 8 + j] = expf(ldb[d * 64 + k * 8 + j] - m);
}

// x -> split-bf16 tiled image. One thread per 16 B chunk.
__global__ __launch_bounds__(256) void conv_x_k(const float* __restrict__ x,
                                                char* __restrict__ scratch) {
    const int gid = blockIdx.x * 256 + threadIdx.x;   // 0..524287
    const int c  = gid & 3;
    const int r  = (gid >> 2) & 63;
    const int kt = (gid >> 8) & 63;
    const int mt = gid >> 14;
    const int h  = (c ^ (r >> 1)) & 3;
    const int m  = mt * 64 + r;
    const int k  = kt * 32 + h * 8;
    const f4* xp = reinterpret_cast<const f4*>(x + (size_t)m * IN_F + k);
    f4 a = xp[0], b = xp[1];
    float v[8] = {a.x, a.y, a.z, a.w, b.x, b.y, b.z, b.w};
    bf16x8 h8, l8;
    #pragma unroll
    for (int i = 0; i < 8; ++i) {
        unsigned short hb = f2bh(v[i]);
        h8[i] = (short)hb;
        l8[i] = (short)f2bh(v[i] - bh2f(hb));
    }
    *reinterpret_cast<bf16x8*>(scratch + (size_t)gid * 16) = h8;
    *reinterpret_cast<bf16x8*>(scratch + (8u << 20) + (size_t)gid * 16) = l8;
}

// w_eff = mask(w)*invnorm[k]*expld[n] -> split-bf16 tiled image ([n][k] tiles).
// Block = one (ct,kt) tile; skip never-read below-diagonal tiles.
__global__ __launch_bounds__(256) void conv_w_k(const float* __restrict__ weight,
                                                const float* __restrict__ invnorm,
                                                const float* __restrict__ expld,
                                                char* __restrict__ scratch) {
    const int blk = blockIdx.x;
    const int ct  = blk >> 6;       // col tile 0..31
    const int kt  = blk & 63;       // k tile 0..63
    if (kt >= 2 * ct + 2) return;   // tile strictly below diagonal: never staged

    __shared__ unsigned short sh_hi[32 * 64], sh_lo[32 * 64];
    const int t  = threadIdx.x;
    const int kr = t >> 3;                 // k row in tile
    const int ns = (t & 7) * 8;            // col seg
    const int k  = kt * 32 + kr;
    const int n0 = ct * 64 + ns;
    const int rk = k >> 3;

    const f4* wp = reinterpret_cast<const f4*>(weight + (size_t)k * OUT_F + n0);
    f4 a = wp[0], b = wp[1];
    f4 e0 = *reinterpret_cast<const f4*>(expld + n0);
    f4 e1 = *reinterpret_cast<const f4*>(expld + n0 + 4);
    const float inv = invnorm[k];
    float vv[8] = {a.x, a.y, a.z, a.w, b.x, b.y, b.z, b.w};
    float ee[8] = {e0.x, e0.y, e0.z, e0.w, e1.x, e1.y, e1.z, e1.w};
    #pragma unroll
    for (int i = 0; i < 8; ++i) {
        int cj = (n0 + i) >> 3;
        float v = (cj < rk) ? 0.0f : ((cj == rk) ? __expf(vv[i]) : vv[i]);
        v *= inv * ee[i];
        unsigned short hb = f2bh(v);
        sh_hi[kr * 64 + ns + i] = hb;
        sh_lo[kr * 64 + ns + i] = f2bh(v - bh2f(hb));
    }
    __syncthreads();

    // emit swizzled chunks: thread t -> (row r = n_local, chunk c)
    const int r = t >> 2, c = t & 3;
    const int h = (c ^ (r >> 1)) & 3;
    bf16x8 oh, ol;
    #pragma unroll
    for (int i = 0; i < 8; ++i) {
        oh[i] = (short)sh_hi[(h * 8 + i) * 64 + r];
        ol[i] = (short)sh_lo[(h * 8 + i) * 64 + r];
    }
    const size_t tb = (size_t)(ct * 64 + kt) * 4096 + (size_t)t * 16;
    *reinterpret_cast<bf16x8*>(scratch + (16u << 20) + tb) = oh;
    *reinterpret_cast<bf16x8*>(scratch + (24u << 20) + tb) = ol;
}

// ------------------------------------------------------------------
// Pure-MFMA GEMM: y = x @ w_eff + bias from precomputed split-bf16 tiles.
// 512 blocks = 32 M-tiles (64 rows) x 16 strip pairs (q, 31-q): constant
// per-block work (792 MFMA/wave). 4 waves; wave = 32 rows x (32L + 32R).
// K-step = 32: stage 6 (or 4) tiles via global_load_lds(16B), 12 b128
// fragment reads, 24 MFMAs (3 per 16x16 tile: hh + lh + hl).
// ------------------------------------------------------------------
#define LDS_STEP 24576
__global__ __launch_bounds__(256, 2) void gemm_mfma2_k(const char* __restrict__ scratch,
                                                       const float* __restrict__ bias,
                                                       float* __restrict__ y) {
    __shared__ __align__(16) char lds[2 * LDS_STEP];

    const int b  = blockIdx.x;
    const int q  = (b & 7) | (((b >> 8) & 1) << 3);   // same-q -> same XCD
    const int mt = (b >> 3) & 31;
    const int m0 = mt * 64;
    const int jL = q * 64, jR = (31 - q) * 64;
    const int ctL = q, ctR = 31 - q;
    const int ntL = 2 * (q + 1), nt = 2 * (32 - q);

    const int tid = threadIdx.x;
    const int l   = tid & 63;
    const int w   = tid >> 6;
    const int wr  = w >> 1, wc = w & 1;
    const int l15 = l & 15, h = l >> 4;

    const char* aHi = scratch;
    const char* aLo = scratch + (8u  << 20);
    const char* bHi = scratch + (16u << 20);
    const char* bLo = scratch + (24u << 20);

    // fragment read offsets (within a 4 KB tile)
    int raA[2], raB[2];
    #pragma unroll
    for (int mi = 0; mi < 2; ++mi) {
        int row = wr * 32 + mi * 16 + l15;
        raA[mi] = row * 64 + (((h ^ (row >> 1)) & 3) << 4);
    }
    #pragma unroll
    for (int nj = 0; nj < 2; ++nj) {
        int row = wc * 32 + nj * 16 + l15;
        raB[nj] = row * 64 + (((h ^ (row >> 1)) & 3) << 4);
    }

    f32x4 acc[2][4];
    #pragma unroll
    for (int mi = 0; mi < 2; ++mi)
        #pragma unroll
        for (int cc = 0; cc < 4; ++cc) acc[mi][cc] = (f32x4)0.0f;

    const int lane16 = tid << 4;           // = wave*1024 + lane*16
    const int wbase  = (tid >> 6) << 10;   // wave-uniform LDS sub-base

    auto STAGE = [&](int buf, int ti) {
        char* lb = lds + buf * LDS_STEP + wbase;
        const size_t at = (size_t)(mt * 64 + ti) * 4096 + lane16;
        gload16(aHi + at, lb);
        gload16(aLo + at, lb + 4096);
        const size_t btR = (size_t)(ctR * 64 + ti) * 4096 + lane16;
        gload16(bHi + btR, lb + 12288);
        gload16(bLo + btR, lb + 20480);
        if (ti < ntL) {
            const size_t btL = (size_t)(ctL * 64 + ti) * 4096 + lane16;
            gload16(bHi + btL, lb + 8192);
            gload16(bLo + btL, lb + 16384);
        }
    };

    STAGE(0, 0);
    __syncthreads();

    int cur = 0;
    for (int ti = 0; ti < nt; ++ti) {
        if (ti + 1 < nt) STAGE(cur ^ 1, ti + 1);
        const char* base = lds + cur * LDS_STEP;
        const bool full = (ti < ntL);
        bf16x8 ah[2], al[2], bh[4], bl[4];
        #pragma unroll
        for (int mi = 0; mi < 2; ++mi) {
            ah[mi] = *reinterpret_cast<const bf16x8*>(base + raA[mi]);
            al[mi] = *reinterpret_cast<const bf16x8*>(base + 4096 + raA[mi]);
        }
        #pragma unroll
        for (int nj = 0; nj < 2; ++nj) {
            bh[2 + nj] = *reinterpret_cast<const bf16x8*>(base + 12288 + raB[nj]);
            bl[2 + nj] = *reinterpret_cast<const bf16x8*>(base + 20480 + raB[nj]);
        }
        if (full) {
            #pragma unroll
            for (int nj = 0; nj < 2; ++nj) {
                bh[nj] = *reinterpret_cast<const bf16x8*>(base + 8192  + raB[nj]);
                bl[nj] = *reinterpret_cast<const bf16x8*>(base + 16384 + raB[nj]);
            }
        }
        #pragma unroll
        for (int mi = 0; mi < 2; ++mi)
            #pragma unroll
            for (int cc = 0; cc < 4; ++cc) {
                if (cc >= 2 || full) {
                    acc[mi][cc] = __builtin_amdgcn_mfma_f32_16x16x32_bf16(ah[mi], bh[cc], acc[mi][cc], 0, 0, 0);
                    acc[mi][cc] = __builtin_amdgcn_mfma_f32_16x16x32_bf16(al[mi], bh[cc], acc[mi][cc], 0, 0, 0);
                    acc[mi][cc] = __builtin_amdgcn_mfma_f32_16x16x32_bf16(ah[mi], bl[cc], acc[mi][cc], 0, 0, 0);
                }
            }
        __syncthreads();
        cur ^= 1;
    }

    // epilogue: + bias (expld/invnorm already folded into the images)
    #pragma unroll
    for (int mi = 0; mi < 2; ++mi)
        #pragma unroll
        for (int cc = 0; cc < 4; ++cc) {
            int col = ((cc < 2) ? jL : jR) + wc * 32 + ((cc & 1) << 4) + l15;
            float bs = bias[col];
            #pragma unroll
            for (int j = 0; j < 4; ++j) {
                int row = m0 + wr * 32 + mi * 16 + (h << 2) + j;
                y[(size_t)row * OUT_F + col] = ((const float*)&acc[mi][cc])[j] + bs;
            }
        }
}

// Streaming 8x8 log-matmul; b128 LDS reads, HW transcendentals.
__global__ __launch_bounds__(256) void accum_k(const float* __restrict__ ab,
                                               const float* __restrict__ eY,
                                               const float* __restrict__ myv,
                                               float* __restrict__ out) {
    __shared__ float lsE[32 * 68];
    __shared__ float lsM[256];

    const int blk = blockIdx.x;
    const int t   = threadIdx.x;
    const int d0  = (blk * 32) & 255;

    #pragma unroll
    for (int hh = 0; hh < 2; ++hh) {
        int idx4 = t + hh * 256;
        int lin  = idx4 * 4;
        int dd = lin >> 6, c = lin & 63;
        f4 v = *reinterpret_cast<const f4*>(eY + d0 * 64 + lin);
        *reinterpret_cast<f4*>(&lsE[dd * 68 + c]) = v;
    }
    lsM[t] = myv[d0 * 8 + t];
    __syncthreads();

    const size_t r = (size_t)blk * 256 + t;
    const f4* lxp = reinterpret_cast<const f4*>(ab + r * 8);
    f4 l0 = lxp[0], l1 = lxp[1];
    float lx[8] = {l0.x, l0.y, l0.z, l0.w, l1.x, l1.y, l1.z, l1.w};

    float mx = lx[0];
    #pragma unroll
    for (int k = 1; k < 8; ++k) mx = fmaxf(mx, lx[k]);
    float el[8];
    #pragma unroll
    for (int k = 0; k < 8; ++k) el[k] = __expf(lx[k] - mx);

    const int dd = t >> 3;
    float s[8] = {0, 0, 0, 0, 0, 0, 0, 0};
    #pragma unroll
    for (int k = 0; k < 8; ++k) {
        float e = el[k];
        f4 r0 = *reinterpret_cast<const f4*>(&lsE[dd * 68 + k * 8]);
        f4 r1 = *reinterpret_cast<const f4*>(&lsE[dd * 68 + k * 8 + 4]);
        s[0] = fmaf(e, r0.x, s[0]); s[1] = fmaf(e, r0.y, s[1]);
        s[2] = fmaf(e, r0.z, s[2]); s[3] = fmaf(e, r0.w, s[3]);
        s[4] = fmaf(e, r1.x, s[4]); s[5] = fmaf(e, r1.y, s[5]);
        s[6] = fmaf(e, r1.z, s[6]); s[7] = fmaf(e, r1.w, s[7]);
    }
    f4 m0v = *reinterpret_cast<const f4*>(&lsM[dd * 8]);
    f4 m1v = *reinterpret_cast<const f4*>(&lsM[dd * 8 + 4]);
    f4 o0, o1;
    o0.x = __logf(s[0]) + mx + m0v.x; o0.y = __logf(s[1]) + mx + m0v.y;
    o0.z = __logf(s[2]) + mx + m0v.z; o0.w = __logf(s[3]) + mx + m0v.w;
    o1.x = __logf(s[4]) + mx + m1v.x; o1.y = __logf(s[5]) + mx + m1v.y;
    o1.z = __logf(s[6]) + mx + m1v.z; o1.w = __logf(s[7]) + mx + m1v.w;
    f4* op = reinterpret_cast<f4*>(out + r * 8);
    op[0] = o0; op[1] = o1;
}

extern "C" void kernel_launch(void* const* d_in, const int* in_sizes, int n_in,
                              void* d_out, int out_size, void* d_ws, size_t ws_size,
                              hipStream_t stream) {
    const float* x        = (const float*)d_in[0];
    const float* ab       = (const float*)d_in[1];
    const float* weight   = (const float*)d_in[2];
    const float* log_diag = (const float*)d_in[3];
    const float* bias     = (const float*)d_in[4];

    float* y     = (float*)d_out;
    float* accum = (float*)d_out + (size_t)BATCH * OUT_F;
    char*  scratch = (char*)accum;   // 32 MB of the 134 MB accum region; fully consumed before accum_k writes

    float* ws      = (float*)d_ws;
    float* invnorm = ws;
    float* ldb     = ws + 2048;
    float* expld   = ws + 18432;
    float* myv     = ws + 20480;
    float* eY      = ws + 22528;

    hipLaunchKernelGGL(prep_rows_k, dim3(2048), dim3(256), 0, stream,
                       weight, log_diag, invnorm, ldb);
    hipLaunchKernelGGL(prep_ldb_k, dim3(8), dim3(256), 0, stream,
                       ldb, log_diag, myv, eY, expld);
    hipLaunchKernelGGL(conv_x_k, dim3(2048), dim3(256), 0, stream, x, scratch);
    hipLaunchKernelGGL(conv_w_k, dim3(2048), dim3(256), 0, stream,
                       weight, invnorm, expld, scratch);
    hipLaunchKernelGGL(gemm_mfma2_k, dim3(512), dim3(256), 0, stream,
                       scratch, bias, y);
    hipLaunchKernelGGL(accum_k, dim3(16384), dim3(256), 0, stream,
                       ab, eY, myv, accum);
}

// Round 7
// 307.873 us; speedup vs baseline: 1.4053x; 1.0280x over previous
//
#include <hip/hip_runtime.h>
#include <math.h>

#define IN_F 2048
#define OUT_F 2048
#define BATCH 2048

typedef float4 f4;
typedef __attribute__((ext_vector_type(4))) float f32x4;
typedef __attribute__((ext_vector_type(8))) short bf16x8;

__device__ __forceinline__ unsigned short f2bh(float f) {   // f32 -> bf16, RNE
    unsigned u = __float_as_uint(f);
    u += 0x7FFF + ((u >> 16) & 1);
    return (unsigned short)(u >> 16);
}
__device__ __forceinline__ float bh2f(unsigned short h) {
    return __uint_as_float(((unsigned)h) << 16);
}

__device__ __forceinline__ void gload16(const char* g, char* l) {
    __builtin_amdgcn_global_load_lds(
        (const __attribute__((address_space(1))) unsigned int*)g,
        (__attribute__((address_space(3))) unsigned int*)l, 16, 0, 0);
}

// ------------------------------------------------------------------
// ws layout: floats [0,38912) tables; split-bf16 images at +1 MB:
//   A_HI@0  A_LO@8M  B_HI@16M  B_LO@24M   (33 MB total of ~576 MiB ws)
// Image tile = 64 rows x 32 k bf16 = 4096 B at (rt*64+kt)*4096; within a
// tile byte = row*64 + chunk*16, chunk c holds k-chunk h=(c^(row>>1))&3.
// This is byte-for-byte the LDS image: global_load_lds copies linearly,
// swizzled ds_read_b128 fragment reads are 2-way (free, m136).
// ------------------------------------------------------------------

__global__ __launch_bounds__(256) void prep_rows_k(const float* __restrict__ weight,
                                                   const float* __restrict__ log_diag,
                                                   float* __restrict__ invnorm,
                                                   float* __restrict__ ldb) {
    const int i  = blockIdx.x;
    const int ri = i >> 3;
    const int t  = threadIdx.x;
    const f4* wrow = reinterpret_cast<const f4*>(weight + (size_t)i * OUT_F);
    f4 v0 = wrow[t * 2];
    f4 v1 = wrow[t * 2 + 1];
    float raw[8] = {v0.x, v0.y, v0.z, v0.w, v1.x, v1.y, v1.z, v1.w};

    float ss = 0.0f;
    if (t == ri) {
        #pragma unroll
        for (int e = 0; e < 8; ++e) { float m = expf(raw[e]); ss += m * m; }
    } else if (t > ri) {
        #pragma unroll
        for (int e = 0; e < 8; ++e) ss += raw[e] * raw[e];
    }
    #pragma unroll
    for (int o = 32; o > 0; o >>= 1) ss += __shfl_xor(ss, o, 64);
    __shared__ float part[4];
    if ((t & 63) == 0) part[t >> 6] = ss;
    __syncthreads();
    float total = part[0] + part[1] + part[2] + part[3];
    float norm  = sqrtf(total);

    if (t == 0) invnorm[i] = 1.0f / norm;
    if (t == ri) {
        float logn = logf(norm);
        int a = i & 7;
        #pragma unroll
        for (int b = 0; b < 8; ++b)
            ldb[ri * 64 + a * 8 + b] = log_diag[ri * 8 + b] + raw[b] - logn;
    }
}

// Fused second stage: conv_x (blocks 0..2047) | conv_w (2048..4095)
// | prep_ldb (4096..4103). All depend only on prep_rows + inputs.
__global__ __launch_bounds__(256) void fused_prep2_k(const float* __restrict__ x,
                                                     const float* __restrict__ weight,
                                                     const float* __restrict__ invnorm,
                                                     const float* __restrict__ ldb,
                                                     const float* __restrict__ log_diag,
                                                     float* __restrict__ myv,
                                                     float* __restrict__ eY,
                                                     float* __restrict__ expld,
                                                     char* __restrict__ scratch) {
    const int b = blockIdx.x;
    const int tid = threadIdx.x;
    if (b < 2048) {
        // ---- conv_x: x -> split-bf16 tiled image, 1 thread / 16B chunk ----
        const int gid = b * 256 + tid;
        const int c  = gid & 3;
        const int r  = (gid >> 2) & 63;
        const int kt = (gid >> 8) & 63;
        const int mt = gid >> 14;
        const int h  = (c ^ (r >> 1)) & 3;
        const int m  = mt * 64 + r;
        const int k  = kt * 32 + h * 8;
        const f4* xp = reinterpret_cast<const f4*>(x + (size_t)m * IN_F + k);
        f4 a = xp[0], bb = xp[1];
        float v[8] = {a.x, a.y, a.z, a.w, bb.x, bb.y, bb.z, bb.w};
        bf16x8 h8, l8;
        #pragma unroll
        for (int i = 0; i < 8; ++i) {
            unsigned short hb = f2bh(v[i]);
            h8[i] = (short)hb;
            l8[i] = (short)f2bh(v[i] - bh2f(hb));
        }
        *reinterpret_cast<bf16x8*>(scratch + (size_t)gid * 16) = h8;
        *reinterpret_cast<bf16x8*>(scratch + (8u << 20) + (size_t)gid * 16) = l8;
    } else if (b < 4096) {
        // ---- conv_w: w_eff -> split-bf16 tiled image ([n][k] tiles) ----
        const int blk = b - 2048;
        const int ct  = blk >> 6;
        const int kt  = blk & 63;
        if (kt >= 2 * ct + 2) return;    // below-diagonal tile: never staged

        __shared__ unsigned short sh_hi[32 * 64], sh_lo[32 * 64];
        const int kr = tid >> 3;
        const int ns = (tid & 7) * 8;
        const int k  = kt * 32 + kr;
        const int n0 = ct * 64 + ns;
        const int rk = k >> 3;

        const f4* wp = reinterpret_cast<const f4*>(weight + (size_t)k * OUT_F + n0);
        f4 a = wp[0], bb = wp[1];
        f4 e0 = *reinterpret_cast<const f4*>(expld + n0);
        f4 e1 = *reinterpret_cast<const f4*>(expld + n0 + 4);
        const float inv = invnorm[k];
        float vv[8] = {a.x, a.y, a.z, a.w, bb.x, bb.y, bb.z, bb.w};
        float ee[8] = {e0.x, e0.y, e0.z, e0.w, e1.x, e1.y, e1.z, e1.w};
        #pragma unroll
        for (int i = 0; i < 8; ++i) {
            int cj = (n0 + i) >> 3;
            float v = (cj < rk) ? 0.0f : ((cj == rk) ? __expf(vv[i]) : vv[i]);
            v *= inv * ee[i];
            unsigned short hb = f2bh(v);
            sh_hi[kr * 64 + ns + i] = hb;
            sh_lo[kr * 64 + ns + i] = f2bh(v - bh2f(hb));
        }
        __syncthreads();

        const int r = tid >> 2, c = tid & 3;
        const int h = (c ^ (r >> 1)) & 3;
        bf16x8 oh, ol;
        #pragma unroll
        for (int i = 0; i < 8; ++i) {
            oh[i] = (short)sh_hi[(h * 8 + i) * 64 + r];
            ol[i] = (short)sh_lo[(h * 8 + i) * 64 + r];
        }
        const size_t tb = (size_t)(ct * 64 + kt) * 4096 + (size_t)tid * 16;
        *reinterpret_cast<bf16x8*>(scratch + (16u << 20) + tb) = oh;
        *reinterpret_cast<bf16x8*>(scratch + (24u << 20) + tb) = ol;
    } else {
        // ---- prep_ldb: my / eY tables ----
        int t = (b - 4096) * 256 + tid;     // 0..2047
        int d = t >> 3, j = t & 7;
        float m = -INFINITY;
        #pragma unroll
        for (int k = 0; k < 8; ++k) m = fmaxf(m, ldb[d * 64 + k * 8 + j]);
        myv[t] = m;
        #pragma unroll
        for (int k = 0; k < 8; ++k) eY[d * 64 + k * 8 + j] = __expf(ldb[d * 64 + k * 8 + j] - m);
    }
}

// expld depends only on log_diag; tiny standalone kernel.
__global__ void prep_expld_k(const float* __restrict__ log_diag,
                             float* __restrict__ expld) {
    int t = blockIdx.x * 256 + threadIdx.x;
    expld[t] = expf(log_diag[t]);
}

// ------------------------------------------------------------------
// Fused main: blocks [0,512) = MFMA GEMM (y), [512,16896) = accum.
// Independent outputs; accum is HBM-bound, gemm hides under it.
// ------------------------------------------------------------------
#define LDS_STEP 24576
__global__ __launch_bounds__(256, 2) void fused_main_k(const char* __restrict__ scratch,
                                                       const float* __restrict__ bias,
                                                       float* __restrict__ y,
                                                       const float* __restrict__ ab,
                                                       const float* __restrict__ eY,
                                                       const float* __restrict__ myv,
                                                       float* __restrict__ out) {
    __shared__ __align__(16) char lds[2 * LDS_STEP];

    if (blockIdx.x < 512) {
        // ================= GEMM path =================
        const int b  = blockIdx.x;
        const int q  = (b & 7) | (((b >> 8) & 1) << 3);
        const int mt = (b >> 3) & 31;
        const int m0 = mt * 64;
        const int jL = q * 64, jR = (31 - q) * 64;
        const int ctL = q, ctR = 31 - q;
        const int ntL = 2 * (q + 1), nt = 2 * (32 - q);

        const int tid = threadIdx.x;
        const int l   = tid & 63;
        const int w   = tid >> 6;
        const int wr  = w >> 1, wc = w & 1;
        const int l15 = l & 15, h = l >> 4;

        const char* aHi = scratch;
        const char* aLo = scratch + (8u  << 20);
        const char* bHi = scratch + (16u << 20);
        const char* bLo = scratch + (24u << 20);

        int raA[2], raB[2];
        #pragma unroll
        for (int mi = 0; mi < 2; ++mi) {
            int row = wr * 32 + mi * 16 + l15;
            raA[mi] = row * 64 + (((h ^ (row >> 1)) & 3) << 4);
        }
        #pragma unroll
        for (int nj = 0; nj < 2; ++nj) {
            int row = wc * 32 + nj * 16 + l15;
            raB[nj] = row * 64 + (((h ^ (row >> 1)) & 3) << 4);
        }

        f32x4 acc[2][4];
        #pragma unroll
        for (int mi = 0; mi < 2; ++mi)
            #pragma unroll
            for (int cc = 0; cc < 4; ++cc) acc[mi][cc] = (f32x4)0.0f;

        const int lane16 = tid << 4;
        const int wbase  = (tid >> 6) << 10;

        auto STAGE = [&](int buf, int ti) {
            char* lb = lds + buf * LDS_STEP + wbase;
            const size_t at = (size_t)(mt * 64 + ti) * 4096 + lane16;
            gload16(aHi + at, lb);
            gload16(aLo + at, lb + 4096);
            const size_t btR = (size_t)(ctR * 64 + ti) * 4096 + lane16;
            gload16(bHi + btR, lb + 12288);
            gload16(bLo + btR, lb + 20480);
            if (ti < ntL) {
                const size_t btL = (size_t)(ctL * 64 + ti) * 4096 + lane16;
                gload16(bHi + btL, lb + 8192);
                gload16(bLo + btL, lb + 16384);
            }
        };

        STAGE(0, 0);
        __syncthreads();

        int cur = 0;
        for (int ti = 0; ti < nt; ++ti) {
            if (ti + 1 < nt) STAGE(cur ^ 1, ti + 1);
            const char* base = lds + cur * LDS_STEP;
            const bool full = (ti < ntL);
            bf16x8 ah[2], al[2], bh[4], bl[4];
            #pragma unroll
            for (int mi = 0; mi < 2; ++mi) {
                ah[mi] = *reinterpret_cast<const bf16x8*>(base + raA[mi]);
                al[mi] = *reinterpret_cast<const bf16x8*>(base + 4096 + raA[mi]);
            }
            #pragma unroll
            for (int nj = 0; nj < 2; ++nj) {
                bh[2 + nj] = *reinterpret_cast<const bf16x8*>(base + 12288 + raB[nj]);
                bl[2 + nj] = *reinterpret_cast<const bf16x8*>(base + 20480 + raB[nj]);
            }
            if (full) {
                #pragma unroll
                for (int nj = 0; nj < 2; ++nj) {
                    bh[nj] = *reinterpret_cast<const bf16x8*>(base + 8192  + raB[nj]);
                    bl[nj] = *reinterpret_cast<const bf16x8*>(base + 16384 + raB[nj]);
                }
            }
            #pragma unroll
            for (int mi = 0; mi < 2; ++mi)
                #pragma unroll
                for (int cc = 0; cc < 4; ++cc) {
                    if (cc >= 2 || full) {
                        acc[mi][cc] = __builtin_amdgcn_mfma_f32_16x16x32_bf16(ah[mi], bh[cc], acc[mi][cc], 0, 0, 0);
                        acc[mi][cc] = __builtin_amdgcn_mfma_f32_16x16x32_bf16(al[mi], bh[cc], acc[mi][cc], 0, 0, 0);
                        acc[mi][cc] = __builtin_amdgcn_mfma_f32_16x16x32_bf16(ah[mi], bl[cc], acc[mi][cc], 0, 0, 0);
                    }
                }
            __syncthreads();
            cur ^= 1;
        }

        #pragma unroll
        for (int mi = 0; mi < 2; ++mi)
            #pragma unroll
            for (int cc = 0; cc < 4; ++cc) {
                int col = ((cc < 2) ? jL : jR) + wc * 32 + ((cc & 1) << 4) + l15;
                float bs = bias[col];
                #pragma unroll
                for (int j = 0; j < 4; ++j) {
                    int row = m0 + wr * 32 + mi * 16 + (h << 2) + j;
                    y[(size_t)row * OUT_F + col] = ((const float*)&acc[mi][cc])[j] + bs;
                }
            }
    } else {
        // ================= accum path =================
        float* lsE = reinterpret_cast<float*>(lds);            // 32*68 floats
        float* lsM = reinterpret_cast<float*>(lds + 8704);     // 256 floats

        const int blk = blockIdx.x - 512;
        const int t   = threadIdx.x;
        const int d0  = (blk * 32) & 255;

        #pragma unroll
        for (int hh = 0; hh < 2; ++hh) {
            int idx4 = t + hh * 256;
            int lin  = idx4 * 4;
            int dd = lin >> 6, c = lin & 63;
            f4 v = *reinterpret_cast<const f4*>(eY + d0 * 64 + lin);
            *reinterpret_cast<f4*>(&lsE[dd * 68 + c]) = v;
        }
        lsM[t] = myv[d0 * 8 + t];
        __syncthreads();

        const size_t r = (size_t)blk * 256 + t;
        const f4* lxp = reinterpret_cast<const f4*>(ab + r * 8);
        f4 l0 = lxp[0], l1 = lxp[1];
        float lx[8] = {l0.x, l0.y, l0.z, l0.w, l1.x, l1.y, l1.z, l1.w};

        float mx = lx[0];
        #pragma unroll
        for (int k = 1; k < 8; ++k) mx = fmaxf(mx, lx[k]);
        float el[8];
        #pragma unroll
        for (int k = 0; k < 8; ++k) el[k] = __expf(lx[k] - mx);

        const int dd = t >> 3;
        float s[8] = {0, 0, 0, 0, 0, 0, 0, 0};
        #pragma unroll
        for (int k = 0; k < 8; ++k) {
            float e = el[k];
            f4 r0 = *reinterpret_cast<const f4*>(&lsE[dd * 68 + k * 8]);
            f4 r1 = *reinterpret_cast<const f4*>(&lsE[dd * 68 + k * 8 + 4]);
            s[0] = fmaf(e, r0.x, s[0]); s[1] = fmaf(e, r0.y, s[1]);
            s[2] = fmaf(e, r0.z, s[2]); s[3] = fmaf(e, r0.w, s[3]);
            s[4] = fmaf(e, r1.x, s[4]); s[5] = fmaf(e, r1.y, s[5]);
            s[6] = fmaf(e, r1.z, s[6]); s[7] = fmaf(e, r1.w, s[7]);
        }
        f4 m0v = *reinterpret_cast<const f4*>(&lsM[dd * 8]);
        f4 m1v = *reinterpret_cast<const f4*>(&lsM[dd * 8 + 4]);
        f4 o0, o1;
        o0.x = __logf(s[0]) + mx + m0v.x; o0.y = __logf(s[1]) + mx + m0v.y;
        o0.z = __logf(s[2]) + mx + m0v.z; o0.w = __logf(s[3]) + mx + m0v.w;
        o1.x = __logf(s[4]) + mx + m1v.x; o1.y = __logf(s[5]) + mx + m1v.y;
        o1.z = __logf(s[6]) + mx + m1v.z; o1.w = __logf(s[7]) + mx + m1v.w;
        f4* op = reinterpret_cast<f4*>(out + r * 8);
        op[0] = o0; op[1] = o1;
    }
}

extern "C" void kernel_launch(void* const* d_in, const int* in_sizes, int n_in,
                              void* d_out, int out_size, void* d_ws, size_t ws_size,
                              hipStream_t stream) {
    const float* x        = (const float*)d_in[0];
    const float* ab       = (const float*)d_in[1];
    const float* weight   = (const float*)d_in[2];
    const float* log_diag = (const float*)d_in[3];
    const float* bias     = (const float*)d_in[4];

    float* y     = (float*)d_out;
    float* accum = (float*)d_out + (size_t)BATCH * OUT_F;

    float* ws      = (float*)d_ws;
    float* invnorm = ws;
    float* ldb     = ws + 2048;
    float* expld   = ws + 18432;
    float* myv     = ws + 20480;
    float* eY      = ws + 22528;
    char*  scratch = (char*)d_ws + (1u << 20);   // 32 MB of images at +1 MB

    hipLaunchKernelGGL(prep_expld_k, dim3(8), dim3(256), 0, stream,
                       log_diag, expld);
    hipLaunchKernelGGL(prep_rows_k, dim3(2048), dim3(256), 0, stream,
                       weight, log_diag, invnorm, ldb);
    hipLaunchKernelGGL(fused_prep2_k, dim3(4104), dim3(256), 0, stream,
                       x, weight, invnorm, ldb, log_diag, myv, eY, expld, scratch);
    hipLaunchKernelGGL(fused_main_k, dim3(16896), dim3(256), 0, stream,
                       scratch, bias, y, ab, eY, myv, accum);
}